// Round 6
// baseline (421.189 us; speedup 1.0000x reference)
//
#include <hip/hip_runtime.h>
#include <hip/hip_bf16.h>

#define BWIN 256
#define NTOK 343
#define CDIM 192
#define NH   6
#define HD   32
#define QKVF 576
#define NROWS (BWIN * NTOK)          // 87808
#define SCALE 0.17677669529663687f   // 1/sqrt(32)
#define LOG2E 1.4426950408889634f

typedef unsigned short u16;
typedef unsigned int   u32;
typedef short bf16x8 __attribute__((ext_vector_type(8)));
typedef float f32x4 __attribute__((ext_vector_type(4)));
typedef unsigned short u16x8 __attribute__((ext_vector_type(8)));

// ws layout (bytes). qkvb is HEAD-MAJOR: [sel(3)][h(6)][rows(87808)][32] u16.
// opb is [h(6)][rows][32] u16. wqb+bqs alias the opb region (dead after
// gemm_qkv; attn then overwrites opb).
#define OFF_QKVB 0UL                 // u16 3*6*87808*32 = 101,154,816
#define OFF_BMB  101154816UL         // u16 [6][22][11][64][8] = 1,485,312 (frag-order bias)
#define OFF_WPB  102640128UL         // u16 [192][192]   =      73,728
#define OFF_OPB  102713856UL         // u16 [6][87808][32] = 33,718,272
#define OFF_WQB  102713856UL         // aliases opb (dead before attn writes)
#define OFF_BQS  102935040UL         // f32 [576] (aliases opb too)
#define WS_NEED  136432128UL

__device__ __forceinline__ u16 f2bf(float f) {
    u32 u = __float_as_uint(f);
    u += 0x7FFFu + ((u >> 16) & 1u);           // RNE
    return (u16)(u >> 16);
}
__device__ __forceinline__ float bf2f(u16 h) {
    return __uint_as_float(((u32)h) << 16);
}
__device__ __forceinline__ u32 pk2bf(float a, float b) {
    union { __hip_bfloat162 h; u32 u; } v;
    v.h = __float22bfloat162_rn(make_float2(a, b));   // lo=a, hi=b
    return v.u;
}

__global__ void ws_too_small_sentinel(float* out) { out[0] = 1.0e6f; }

// ---------------------------------------------------------------- small converts
// bias in MFMA-fragment order: [h][qt(22)][jc(11)][lane(64)][8],
// e<4 -> j = jc*32 + g*4 + e ; e>=4 -> j = jc*32 + 16 + g*4 + (e-4),
// q = qt*16 + cl (clamped; q-pad lanes' outputs discarded).
// j >= 343 gets -10000 (masks junk K rows after exp2).
__global__ __launch_bounds__(256) void cvt_small(
    const float* __restrict__ wq, const float* __restrict__ wp,
    const float* __restrict__ bq, const float* __restrict__ btab,
    const int* __restrict__ ridx,
    u16* __restrict__ wqb, u16* __restrict__ wpb,
    float* __restrict__ bqs, u16* __restrict__ bmb)
{
    const int i = blockIdx.x * 256 + threadIdx.x;
    if (i < 110592) {                                 // w_qkv; q rows scaled
        const int f = i / 192;
        wqb[i] = f2bf(wq[i] * (f < CDIM ? SCALE * LOG2E : 1.0f));
    } else if (i < 147456) {
        wpb[i - 110592] = f2bf(wp[i - 110592]);
    } else if (i < 148032) {
        const int f = i - 147456;
        bqs[f] = bq[f] * (f < CDIM ? SCALE * LOG2E : 1.0f);
    } else if (i < 890688) {                          // frag-order bias
        const int u = i - 148032;                     // [0, 742656)
        const int hh = u / 123904;                    // 22*11*512
        const int rem = u - hh * 123904;
        const int qt = rem / 5632;                    // 11*512
        const int rem2 = rem - qt * 5632;
        const int jc = rem2 >> 9;
        const int t = rem2 & 511;
        const int lane = t >> 3, e = t & 7;
        const int cl = lane & 15, g = lane >> 4;
        const int q = min(qt * 16 + cl, NTOK - 1);
        const int j = jc * 32 + ((e < 4) ? (g * 4 + e) : (16 + g * 4 + (e - 4)));
        const float v = (j < NTOK) ? btab[ridx[q * NTOK + j] * NH + hh] * LOG2E
                                   : -10000.0f;
        bmb[u] = f2bf(v);
    }
}

// ---------------------------------------------------------------- qkv GEMM
// X tile (128 rows x full K=192) staged ONCE into LDS (f32->bf16 fused).
// W fragments read from global (37KB f-chunk, L1/L2-resident). Barrier-free
// K-loop. Epilogue stores head-major: 3 dense 8KB chunks per block.
__global__ __launch_bounds__(256, 3) void gemm_qkv(
    const float* __restrict__ x, const u16* __restrict__ wqb,
    const float* __restrict__ bqs, u16* __restrict__ qkvb)
{
    __shared__ __align__(16) u16 smem[128 * 200];     // Xs [128][200]; epilogue Ct [128][104]
    u16* Xs = smem;
    u16* Ct = smem;
    const int f0 = blockIdx.x * 96, m0 = blockIdx.y * 128;
    const int tid = threadIdx.x;
    const int wave = tid >> 6, lane = tid & 63, g = lane >> 4, cl = lane & 15;
    const int wm = (wave >> 1) * 64, wf = (wave & 1) * 48;

    // stage X once: 128 rows x 48 float4 units = 6144 (24 passes of 256)
    #pragma unroll
    for (int p = 0; p < 24; ++p) {
        const int u = tid + 256 * p;
        const int row = u / 48, c = u - row * 48;
        const float4 v = *(const float4*)(x + (size_t)(m0 + row) * CDIM + c * 4);
        *(uint2*)(Xs + row * 200 + c * 4) = make_uint2(pk2bf(v.x, v.y), pk2bf(v.z, v.w));
    }
    __syncthreads();

    f32x4 acc[4][3];
    #pragma unroll
    for (int t = 0; t < 4; ++t)
        #pragma unroll
        for (int s = 0; s < 3; ++s) acc[t][s] = (f32x4){0.f, 0.f, 0.f, 0.f};

    const u16* wbase = wqb + (size_t)(f0 + wf + cl) * CDIM + g * 8;
    #pragma unroll
    for (int kk = 0; kk < 6; ++kk) {
        const int kcol = kk * 32;
        bf16x8 a[4], bb[3];
        #pragma unroll
        for (int s = 0; s < 3; ++s)
            bb[s] = *(const bf16x8*)(wbase + (size_t)(s * 16) * CDIM + kcol);
        #pragma unroll
        for (int t = 0; t < 4; ++t)
            a[t] = *(const bf16x8*)(Xs + (wm + t * 16 + cl) * 200 + kcol + g * 8);
        #pragma unroll
        for (int t = 0; t < 4; ++t)
            #pragma unroll
            for (int s = 0; s < 3; ++s)
                acc[t][s] = __builtin_amdgcn_mfma_f32_16x16x32_bf16(a[t], bb[s], acc[t][s], 0, 0, 0);
    }

    __syncthreads();                                  // Xs reads done; reuse as Ct
    #pragma unroll
    for (int s = 0; s < 3; ++s) {
        const float bv = bqs[f0 + wf + s * 16 + cl];
        #pragma unroll
        for (int t = 0; t < 4; ++t) {
            const int row = wm + t * 16 + g * 4;
            const int col = wf + s * 16 + cl;
            const u32 p01 = pk2bf(acc[t][s][0] + bv, acc[t][s][1] + bv);
            const u32 p23 = pk2bf(acc[t][s][2] + bv, acc[t][s][3] + bv);
            Ct[(row + 0) * 104 + col] = (u16)p01;
            Ct[(row + 1) * 104 + col] = (u16)(p01 >> 16);
            Ct[(row + 2) * 104 + col] = (u16)p23;
            Ct[(row + 3) * 104 + col] = (u16)(p23 >> 16);
        }
    }
    __syncthreads();
    #pragma unroll
    for (int p = 0; p < 6; ++p) {                     // head-major dense stores
        const int u = tid + 256 * p;
        const int row = u / 12, c = u - row * 12;
        const int idx = f0 + c * 8;                   // global f index
        const int sel = idx / 192;
        const int rem = idx - sel * 192;
        const int hh  = rem >> 5;
        const int dd  = rem & 31;
        *(float4*)(qkvb + ((size_t)(sel * NH + hh) * NROWS + m0 + row) * HD + dd) =
            *(const float4*)(Ct + row * 104 + c * 8);
    }
}

// ---------------------------------------------------------------- attention
// Head-major slices: Q/K/V each 22KB contiguous per (b,h). V staged in LDS
// (transposed sigma slots); K read per-jc from global (dense 1KB/wave lines,
// L1/L2-hit, de-clamped: rows>=343 read next slice's data, masked by -10000
// j-pad bias). Bias = frag-order coalesced. O writes dense full lines.
__global__ __launch_bounds__(256, 4) void attn_mfma(
    const u16* __restrict__ qkvb, const u16* __restrict__ bmb,
    u16* __restrict__ opb)
{
    __shared__ u16 Vt[HD][352];      // [d][j-slot] 22528 B
    __shared__ u16 Os[4][16][32];    // per-wave O staging 4096 B
    const int b = blockIdx.x, h = blockIdx.y;
    const int tid = threadIdx.x;
    const int wave = tid >> 6, lane = tid & 63, g = lane >> 4, cl = lane & 15;
    const size_t rowbase = (size_t)b * NTOK;
    const u16* __restrict__ qptr = qkvb + ((size_t)h * NROWS + rowbase) * HD;
    const u16* __restrict__ kptr = qkvb + ((size_t)(NH + h) * NROWS + rowbase) * HD;
    const u16* __restrict__ vptr = qkvb + ((size_t)(2 * NH + h) * NROWS + rowbase) * HD;

    for (int u = tid; u < 1408; u += 256) {           // V stage, sigma slots
        const int row = u >> 2, seg = u & 3;
        union { float4 f; u16 hx[8]; } vv;
        vv.f = make_float4(0.f, 0.f, 0.f, 0.f);
        if (row < NTOK)
            vv.f = *(const float4*)(vptr + (size_t)row * HD + seg * 8);
        const int jl = row & 31;
        const int slot = (jl < 16) ? ((jl >> 2) << 3) + (jl & 3)
                                   : (((jl - 16) >> 2) << 3) + 4 + (jl & 3);
        const int pcol = (row & ~31) + slot;
        #pragma unroll
        for (int e = 0; e < 8; ++e) Vt[seg * 8 + e][pcol] = vv.hx[e];
    }
    __syncthreads();

    bf16x8 ones;
    #pragma unroll
    for (int e = 0; e < 8; ++e) ones[e] = (short)0x3F80;

    for (int base = wave * 2; base < 22; base += 8) { // 11 pairs total
        const int q0a = base * 16, q0b = q0a + 16;
        const bf16x8 qa0 = *(const bf16x8*)(qptr + (size_t)min(q0a + cl, NTOK - 1) * HD + g * 8);
        const bf16x8 qa1 = *(const bf16x8*)(qptr + (size_t)min(q0b + cl, NTOK - 1) * HD + g * 8);
        const u16* bpA = bmb + ((size_t)(h * 22 + base) * 11) * 512 + lane * 8;
        const u16* bpB = bpA + 5632;                  // next q-tile (11*512)

        bf16x8 kb0 = *(const bf16x8*)(kptr + (size_t)cl * HD + g * 8);
        bf16x8 kb1 = *(const bf16x8*)(kptr + (size_t)(16 + cl) * HD + g * 8);
        u16x8 bA = *(const u16x8*)(bpA);
        u16x8 bB = *(const u16x8*)(bpB);

        f32x4 oA0 = {0,0,0,0}, oA1 = {0,0,0,0}, lA = {0,0,0,0};
        f32x4 oB0 = {0,0,0,0}, oB1 = {0,0,0,0}, lB = {0,0,0,0};

        for (int jc = 0; jc < 11; ++jc) {
            const int j0 = jc * 32;
            const bf16x8 ck0 = kb0, ck1 = kb1;
            const u16x8 cA = bA, cB = bB;
            if (jc < 10) {
                const int jn = j0 + 32;
                kb0 = *(const bf16x8*)(kptr + (size_t)(jn + cl) * HD + g * 8);
                kb1 = *(const bf16x8*)(kptr + (size_t)(jn + 16 + cl) * HD + g * 8);
                bA = *(const u16x8*)(bpA + (jc + 1) * 512);
                bB = *(const u16x8*)(bpB + (jc + 1) * 512);
            }
            const bf16x8 vb0 = *(const bf16x8*)&Vt[cl][j0 + g * 8];
            const bf16x8 vb1 = *(const bf16x8*)&Vt[16 + cl][j0 + g * 8];

            {
                f32x4 c0 = { bf2f(cA[0]), bf2f(cA[1]), bf2f(cA[2]), bf2f(cA[3]) };
                f32x4 c1 = { bf2f(cA[4]), bf2f(cA[5]), bf2f(cA[6]), bf2f(cA[7]) };
                const f32x4 s0 = __builtin_amdgcn_mfma_f32_16x16x32_bf16(ck0, qa0, c0, 0, 0, 0);
                const f32x4 s1 = __builtin_amdgcn_mfma_f32_16x16x32_bf16(ck1, qa0, c1, 0, 0, 0);
                union { bf16x8 v; u32 w[4]; } pa;
                pa.w[0] = pk2bf(__builtin_amdgcn_exp2f(s0[0]), __builtin_amdgcn_exp2f(s0[1]));
                pa.w[1] = pk2bf(__builtin_amdgcn_exp2f(s0[2]), __builtin_amdgcn_exp2f(s0[3]));
                pa.w[2] = pk2bf(__builtin_amdgcn_exp2f(s1[0]), __builtin_amdgcn_exp2f(s1[1]));
                pa.w[3] = pk2bf(__builtin_amdgcn_exp2f(s1[2]), __builtin_amdgcn_exp2f(s1[3]));
                oA0 = __builtin_amdgcn_mfma_f32_16x16x32_bf16(pa.v, vb0, oA0, 0, 0, 0);
                oA1 = __builtin_amdgcn_mfma_f32_16x16x32_bf16(pa.v, vb1, oA1, 0, 0, 0);
                lA  = __builtin_amdgcn_mfma_f32_16x16x32_bf16(pa.v, ones, lA, 0, 0, 0);
            }
            {
                f32x4 c0 = { bf2f(cB[0]), bf2f(cB[1]), bf2f(cB[2]), bf2f(cB[3]) };
                f32x4 c1 = { bf2f(cB[4]), bf2f(cB[5]), bf2f(cB[6]), bf2f(cB[7]) };
                const f32x4 s0 = __builtin_amdgcn_mfma_f32_16x16x32_bf16(ck0, qa1, c0, 0, 0, 0);
                const f32x4 s1 = __builtin_amdgcn_mfma_f32_16x16x32_bf16(ck1, qa1, c1, 0, 0, 0);
                union { bf16x8 v; u32 w[4]; } pa;
                pa.w[0] = pk2bf(__builtin_amdgcn_exp2f(s0[0]), __builtin_amdgcn_exp2f(s0[1]));
                pa.w[1] = pk2bf(__builtin_amdgcn_exp2f(s0[2]), __builtin_amdgcn_exp2f(s0[3]));
                pa.w[2] = pk2bf(__builtin_amdgcn_exp2f(s1[0]), __builtin_amdgcn_exp2f(s1[1]));
                pa.w[3] = pk2bf(__builtin_amdgcn_exp2f(s1[2]), __builtin_amdgcn_exp2f(s1[3]));
                oB0 = __builtin_amdgcn_mfma_f32_16x16x32_bf16(pa.v, vb0, oB0, 0, 0, 0);
                oB1 = __builtin_amdgcn_mfma_f32_16x16x32_bf16(pa.v, vb1, oB1, 0, 0, 0);
                lB  = __builtin_amdgcn_mfma_f32_16x16x32_bf16(pa.v, ones, lB, 0, 0, 0);
            }
        }
        #pragma unroll
        for (int half = 0; half < 2; ++half) {
            const f32x4 o0 = half ? oB0 : oA0;
            const f32x4 o1 = half ? oB1 : oA1;
            const f32x4 lc = half ? lB : lA;
            const int q0 = half ? q0b : q0a;
            #pragma unroll
            for (int r = 0; r < 4; ++r) {
                const float inv = 1.0f / lc[r];
                Os[wave][g * 4 + r][cl]      = f2bf(o0[r] * inv);
                Os[wave][g * 4 + r][16 + cl] = f2bf(o1[r] * inv);
            }
            const int row = lane >> 2, cg = (lane & 3) * 8;
            const int q = q0 + row;
            if (q < NTOK)
                *(float4*)(opb + ((size_t)h * NROWS + rowbase + q) * HD + cg) =
                    *(const float4*)&Os[wave][row][cg];
        }
    }
}

// ---------------------------------------------------------------- proj GEMM
// A tile staged from head-major opb (6 dense 8KB chunks), W frags from
// global, barrier-free K-loop, f32 out via 2-pass LDS-transpose epilogue.
__global__ __launch_bounds__(256, 3) void gemm_proj(
    const u16* __restrict__ opb, const u16* __restrict__ wpb,
    const float* __restrict__ bp, float* __restrict__ out)
{
    __shared__ __align__(16) u16 smem[128 * 200];
    u16*   Xs = smem;
    float* Cf = (float*)smem;                         // [64][104] f32
    const int f0 = blockIdx.x * 96, m0 = blockIdx.y * 128;
    const int tid = threadIdx.x;
    const int wave = tid >> 6, lane = tid & 63, g = lane >> 4, cl = lane & 15;
    const int wm = (wave >> 1) * 64, wf = (wave & 1) * 48;

    // stage once: 128 rows x 24 float4 units; unit c -> head c>>2, d (c&3)*8
    #pragma unroll
    for (int p = 0; p < 12; ++p) {
        const int u = tid + 256 * p;
        const int row = u / 24, c = u - row * 24;
        *(float4*)(Xs + row * 200 + c * 8) =
            *(const float4*)(opb + ((size_t)(c >> 2) * NROWS + m0 + row) * HD + (c & 3) * 8);
    }
    __syncthreads();

    f32x4 acc[4][3];
    #pragma unroll
    for (int t = 0; t < 4; ++t)
        #pragma unroll
        for (int s = 0; s < 3; ++s) acc[t][s] = (f32x4){0.f, 0.f, 0.f, 0.f};

    const u16* wbase = wpb + (size_t)(f0 + wf + cl) * CDIM + g * 8;
    #pragma unroll
    for (int kk = 0; kk < 6; ++kk) {
        const int kcol = kk * 32;
        bf16x8 a[4], bb[3];
        #pragma unroll
        for (int s = 0; s < 3; ++s)
            bb[s] = *(const bf16x8*)(wbase + (size_t)(s * 16) * CDIM + kcol);
        #pragma unroll
        for (int t = 0; t < 4; ++t)
            a[t] = *(const bf16x8*)(Xs + (wm + t * 16 + cl) * 200 + kcol + g * 8);
        #pragma unroll
        for (int t = 0; t < 4; ++t)
            #pragma unroll
            for (int s = 0; s < 3; ++s)
                acc[t][s] = __builtin_amdgcn_mfma_f32_16x16x32_bf16(a[t], bb[s], acc[t][s], 0, 0, 0);
    }

    #pragma unroll
    for (int half = 0; half < 2; ++half) {
        __syncthreads();
        if ((wave >> 1) == half) {
            #pragma unroll
            for (int s = 0; s < 3; ++s) {
                const float bv = bp[f0 + wf + s * 16 + cl];
                #pragma unroll
                for (int t = 0; t < 4; ++t)
                    #pragma unroll
                    for (int r = 0; r < 4; ++r)
                        Cf[(t * 16 + g * 4 + r) * 104 + wf + s * 16 + cl] = acc[t][s][r] + bv;
            }
        }
        __syncthreads();
        #pragma unroll
        for (int p = 0; p < 6; ++p) {
            const int u = tid + 256 * p;
            const int row = u / 24, c = u - row * 24;
            *(float4*)(out + (size_t)(m0 + half * 64 + row) * CDIM + f0 + c * 4) =
                *(const float4*)(Cf + row * 104 + c * 4);
        }
    }
}

// ---------------------------------------------------------------- launch
extern "C" void kernel_launch(void* const* d_in, const int* in_sizes, int n_in,
                              void* d_out, int out_size, void* d_ws, size_t ws_size,
                              hipStream_t stream) {
    const float* x     = (const float*)d_in[0];
    const float* wqkv  = (const float*)d_in[1];
    const float* bqkv  = (const float*)d_in[2];
    const float* wproj = (const float*)d_in[3];
    const float* bproj = (const float*)d_in[4];
    const float* btab  = (const float*)d_in[5];
    const int*   ridx  = (const int*)d_in[6];
    float* out = (float*)d_out;

    if (ws_size < WS_NEED) {
        hipLaunchKernelGGL(ws_too_small_sentinel, dim3(1), dim3(1), 0, stream, out);
        return;
    }
    char* ws = (char*)d_ws;
    u16*   qkvb = (u16*)(ws + OFF_QKVB);
    u16*   wqb  = (u16*)(ws + OFF_WQB);
    u16*   wpb  = (u16*)(ws + OFF_WPB);
    float* bqs  = (float*)(ws + OFF_BQS);
    u16*   bmb  = (u16*)(ws + OFF_BMB);
    u16*   opb  = (u16*)(ws + OFF_OPB);

    hipLaunchKernelGGL(cvt_small, dim3(3480), dim3(256), 0, stream,
                       wqkv, wproj, bqkv, btab, ridx, wqb, wpb, bqs, bmb);
    hipLaunchKernelGGL(gemm_qkv, dim3(6, NROWS / 128), dim3(256), 0, stream,
                       x, wqb, bqs, qkvb);
    hipLaunchKernelGGL(attn_mfma, dim3(BWIN, NH), dim3(256), 0, stream,
                       qkvb, bmb, opb);
    hipLaunchKernelGGL(gemm_proj, dim3(2, NROWS / 128), dim3(256), 0, stream,
                       opb, wpb, bproj, out);
}

// Round 7
// 284.290 us; speedup vs baseline: 1.4815x; 1.4815x over previous
//
#include <hip/hip_runtime.h>
#include <hip/hip_bf16.h>

#define BWIN 256
#define NTOK 343
#define CDIM 192
#define NH   6
#define HD   32
#define QKVF 576
#define NROWS (BWIN * NTOK)          // 87808
#define SCALE 0.17677669529663687f   // 1/sqrt(32)
#define LOG2E 1.4426950408889634f

typedef unsigned short u16;
typedef unsigned int   u32;
typedef short bf16x8 __attribute__((ext_vector_type(8)));
typedef float f32x4 __attribute__((ext_vector_type(4)));
typedef unsigned short u16x8 __attribute__((ext_vector_type(8)));

// ws layout (bytes). Interleaved qkvb [row][576] (R0 layout — the 6 head-
// blocks per window share cache lines on the same XCD; load-bearing for
// FETCH). wqb+bqs alias the opb head: dead after gemm_qkv, before attn
// writes opb. All three small tables are in MFMA-fragment order.
#define OFF_QKVB 0UL                 // u16 [87808][576] = 101,154,816
#define OFF_OPB  101154816UL         // u16 [87808][192] =  33,718,272
#define OFF_WQB  101154816UL         // u16 [36][6][64][8] = 221,184 (aliases opb)
#define OFF_BQS  101376000UL         // f32 [576] (aliases opb)
#define OFF_BMB  134873088UL         // u16 [6][22][11][64][8] = 1,486,848
#define OFF_WPB  136359936UL         // u16 [12][6][64][8] = 73,728
#define WS_NEED  136433664UL

__device__ __forceinline__ u16 f2bf(float f) {
    u32 u = __float_as_uint(f);
    u += 0x7FFFu + ((u >> 16) & 1u);           // RNE
    return (u16)(u >> 16);
}
__device__ __forceinline__ float bf2f(u16 h) {
    return __uint_as_float(((u32)h) << 16);
}
__device__ __forceinline__ u32 pk2bf(float a, float b) {
    union { __hip_bfloat162 h; u32 u; } v;
    v.h = __float22bfloat162_rn(make_float2(a, b));   // lo=a, hi=b
    return v.u;
}

__global__ void ws_too_small_sentinel(float* out) { out[0] = 1.0e6f; }

// ---------------------------------------------------------------- small converts
// Frag-order tables. W (both): [fb][kk][lane][8] where lane=(g<<4)|cl holds
// W[fb*16+cl][kk*32+g*8+e] — one coalesced bf16x8/lane B-fragment load.
// Bias: [h][qt(22)][jc(11)][lane][8], e<4 -> j=jc*32+g*4+e, e>=4 ->
// j=jc*32+16+g*4+(e-4); q=qt*16+cl clamped (pad outputs discarded);
// j>=343 = -10000 (validated in R5/R6).
__global__ __launch_bounds__(256) void cvt_small(
    const float* __restrict__ wq, const float* __restrict__ wp,
    const float* __restrict__ bq, const float* __restrict__ btab,
    const int* __restrict__ ridx,
    u16* __restrict__ wqb, u16* __restrict__ wpb,
    float* __restrict__ bqs, u16* __restrict__ bmb)
{
    const int i = blockIdx.x * 256 + threadIdx.x;
    if (i < 110592) {                                 // w_qkv -> frag order
        const int fb = i / 3072;                      // 6*512
        const int r1 = i - fb * 3072;
        const int kk = r1 >> 9;
        const int t  = r1 & 511;
        const int lane = t >> 3, e = t & 7;
        const int row = fb * 16 + (lane & 15);
        const int k   = kk * 32 + (lane >> 4) * 8 + e;
        wqb[i] = f2bf(wq[row * 192 + k] * (row < CDIM ? SCALE * LOG2E : 1.0f));
    } else if (i < 147456) {                          // w_proj -> frag order
        const int u = i - 110592;
        const int fb = u / 3072;
        const int r1 = u - fb * 3072;
        const int kk = r1 >> 9;
        const int t  = r1 & 511;
        const int lane = t >> 3, e = t & 7;
        const int row = fb * 16 + (lane & 15);
        const int k   = kk * 32 + (lane >> 4) * 8 + e;
        wpb[u] = f2bf(wp[row * 192 + k]);
    } else if (i < 148032) {
        const int f = i - 147456;
        bqs[f] = bq[f] * (f < CDIM ? SCALE * LOG2E : 1.0f);
    } else if (i < 891456) {                          // frag-order bias
        const int u = i - 148032;                     // [0, 743424)
        const int hh = u / 123904;                    // 22*11*512
        const int rem = u - hh * 123904;
        const int qt = rem / 5632;                    // 11*512
        const int rem2 = rem - qt * 5632;
        const int jc = rem2 >> 9;
        const int t = rem2 & 511;
        const int lane = t >> 3, e = t & 7;
        const int cl = lane & 15, g = lane >> 4;
        const int q = min(qt * 16 + cl, NTOK - 1);
        const int j = jc * 32 + ((e < 4) ? (g * 4 + e) : (16 + g * 4 + (e - 4)));
        const float v = (j < NTOK) ? btab[ridx[q * NTOK + j] * NH + hh] * LOG2E
                                   : -10000.0f;
        bmb[u] = f2bf(v);
    }
}

// ---------------------------------------------------------------- qkv GEMM
// X tile (128 rows x full K=192) staged ONCE into LDS (f32->bf16 fused).
// W fragments: ONE coalesced 16B/lane load from the frag-order table
// (was a 16-line gather at 384B row stride). Barrier-free K-loop.
__global__ __launch_bounds__(256, 3) void gemm_qkv(
    const float* __restrict__ x, const u16* __restrict__ wqb,
    const float* __restrict__ bqs, u16* __restrict__ qkvb)
{
    __shared__ __align__(16) u16 smem[128 * 200];     // Xs [128][200]; epilogue Ct [128][104]
    u16* Xs = smem;
    u16* Ct = smem;
    const int f0 = blockIdx.x * 96, m0 = blockIdx.y * 128;
    const int tid = threadIdx.x;
    const int wave = tid >> 6, lane = tid & 63, g = lane >> 4, cl = lane & 15;
    const int wm = (wave >> 1) * 64, wf = (wave & 1) * 48;

    // stage X once: 128 rows x 48 float4 units = 6144 (24 passes of 256)
    #pragma unroll
    for (int p = 0; p < 24; ++p) {
        const int u = tid + 256 * p;
        const int row = u / 48, c = u - row * 48;
        const float4 v = *(const float4*)(x + (size_t)(m0 + row) * CDIM + c * 4);
        *(uint2*)(Xs + row * 200 + c * 4) = make_uint2(pk2bf(v.x, v.y), pk2bf(v.z, v.w));
    }
    __syncthreads();

    f32x4 acc[4][3];
    #pragma unroll
    for (int t = 0; t < 4; ++t)
        #pragma unroll
        for (int s = 0; s < 3; ++s) acc[t][s] = (f32x4){0.f, 0.f, 0.f, 0.f};

    const u16* wbase = wqb + (size_t)(blockIdx.x * 6 + (wave & 1) * 3) * 3072 + lane * 8;
    #pragma unroll
    for (int kk = 0; kk < 6; ++kk) {
        const int kcol = kk * 32;
        bf16x8 a[4], bb[3];
        #pragma unroll
        for (int s = 0; s < 3; ++s)
            bb[s] = *(const bf16x8*)(wbase + s * 3072 + kk * 512);
        #pragma unroll
        for (int t = 0; t < 4; ++t)
            a[t] = *(const bf16x8*)(Xs + (wm + t * 16 + cl) * 200 + kcol + g * 8);
        #pragma unroll
        for (int t = 0; t < 4; ++t)
            #pragma unroll
            for (int s = 0; s < 3; ++s)
                acc[t][s] = __builtin_amdgcn_mfma_f32_16x16x32_bf16(a[t], bb[s], acc[t][s], 0, 0, 0);
    }

    __syncthreads();                                  // Xs reads done; reuse as Ct
    #pragma unroll
    for (int s = 0; s < 3; ++s) {
        const float bv = bqs[f0 + wf + s * 16 + cl];
        #pragma unroll
        for (int t = 0; t < 4; ++t) {
            const int row = wm + t * 16 + g * 4;
            const int col = wf + s * 16 + cl;
            const u32 p01 = pk2bf(acc[t][s][0] + bv, acc[t][s][1] + bv);
            const u32 p23 = pk2bf(acc[t][s][2] + bv, acc[t][s][3] + bv);
            Ct[(row + 0) * 104 + col] = (u16)p01;
            Ct[(row + 1) * 104 + col] = (u16)(p01 >> 16);
            Ct[(row + 2) * 104 + col] = (u16)p23;
            Ct[(row + 3) * 104 + col] = (u16)(p23 >> 16);
        }
    }
    __syncthreads();
    #pragma unroll
    for (int p = 0; p < 6; ++p) {                     // coalesced 16B stores
        const int u = tid + 256 * p;
        const int row = u / 12, c = u - row * 12;
        *(float4*)(qkvb + (size_t)(m0 + row) * QKVF + f0 + c * 8) =
            *(const float4*)(Ct + row * 104 + c * 8);
    }
}

// ---------------------------------------------------------------- attention
// R0-verbatim structure (interleaved layout, clamps, occ 4) EXCEPT the bias
// loads: one coalesced u16x8/lane from the frag-order table (was 4x 16-line
// gathers per jc at 704B row stride).
__global__ __launch_bounds__(256, 4) void attn_mfma(
    const u16* __restrict__ qkvb, const u16* __restrict__ bmb,
    u16* __restrict__ opb)
{
    __shared__ u16 Vt[HD][360];      // [d][j-slot] 23040 B
    __shared__ u16 Os[4][16][32];    // per-wave O staging 4096 B
    const int b = blockIdx.x, h = blockIdx.y;
    const int tid = threadIdx.x;
    const int wave = tid >> 6, lane = tid & 63, g = lane >> 4, cl = lane & 15;
    const size_t rowbase = (size_t)b * NTOK;

    for (int u = tid; u < 1408; u += 256) {           // V stage, sigma slots
        const int row = u >> 2, seg = u & 3;
        union { float4 f; u16 hx[8]; } vv;
        vv.f = make_float4(0.f, 0.f, 0.f, 0.f);
        if (row < NTOK)
            vv.f = *(const float4*)(qkvb + (rowbase + row) * QKVF + 2 * CDIM + h * HD + seg * 8);
        const int jl = row & 31;
        const int slot = (jl < 16) ? ((jl >> 2) << 3) + (jl & 3)
                                   : (((jl - 16) >> 2) << 3) + 4 + (jl & 3);
        const int pcol = (row & ~31) + slot;
        #pragma unroll
        for (int e = 0; e < 8; ++e) Vt[seg * 8 + e][pcol] = vv.hx[e];
    }
    __syncthreads();

    bf16x8 ones;
    #pragma unroll
    for (int e = 0; e < 8; ++e) ones[e] = (short)0x3F80;

    for (int base = wave * 2; base < 22; base += 8) { // 11 pairs total
        const int q0a = base * 16, q0b = q0a + 16;
        const bf16x8 qa0 = *(const bf16x8*)(qkvb + (rowbase + min(q0a + cl, NTOK - 1)) * QKVF + h * HD + g * 8);
        const bf16x8 qa1 = *(const bf16x8*)(qkvb + (rowbase + min(q0b + cl, NTOK - 1)) * QKVF + h * HD + g * 8);
        const u16* bpA = bmb + ((size_t)(h * 22 + base) * 11) * 512 + lane * 8;
        const u16* bpB = bpA + 5632;                  // next q-tile (11*512)

        bf16x8 kb0 = *(const bf16x8*)(qkvb + (rowbase + cl) * QKVF + CDIM + h * HD + g * 8);
        bf16x8 kb1 = *(const bf16x8*)(qkvb + (rowbase + 16 + cl) * QKVF + CDIM + h * HD + g * 8);
        u16x8 bA = *(const u16x8*)(bpA);
        u16x8 bB = *(const u16x8*)(bpB);

        f32x4 oA0 = {0,0,0,0}, oA1 = {0,0,0,0}, lA = {0,0,0,0};
        f32x4 oB0 = {0,0,0,0}, oB1 = {0,0,0,0}, lB = {0,0,0,0};

        for (int jc = 0; jc < 11; ++jc) {
            const int j0 = jc * 32;
            const bf16x8 ck0 = kb0, ck1 = kb1;
            const u16x8 cA = bA, cB = bB;
            if (jc < 10) {
                const int jn = j0 + 32;
                kb0 = *(const bf16x8*)(qkvb + (rowbase + min(jn + cl, NTOK - 1)) * QKVF + CDIM + h * HD + g * 8);
                kb1 = *(const bf16x8*)(qkvb + (rowbase + min(jn + 16 + cl, NTOK - 1)) * QKVF + CDIM + h * HD + g * 8);
                bA = *(const u16x8*)(bpA + (jc + 1) * 512);
                bB = *(const u16x8*)(bpB + (jc + 1) * 512);
            }
            const bf16x8 vb0 = *(const bf16x8*)&Vt[cl][j0 + g * 8];
            const bf16x8 vb1 = *(const bf16x8*)&Vt[16 + cl][j0 + g * 8];

            {
                f32x4 c0 = { bf2f(cA[0]), bf2f(cA[1]), bf2f(cA[2]), bf2f(cA[3]) };
                f32x4 c1 = { bf2f(cA[4]), bf2f(cA[5]), bf2f(cA[6]), bf2f(cA[7]) };
                const f32x4 s0 = __builtin_amdgcn_mfma_f32_16x16x32_bf16(ck0, qa0, c0, 0, 0, 0);
                const f32x4 s1 = __builtin_amdgcn_mfma_f32_16x16x32_bf16(ck1, qa0, c1, 0, 0, 0);
                union { bf16x8 v; u32 w[4]; } pa;
                pa.w[0] = pk2bf(__builtin_amdgcn_exp2f(s0[0]), __builtin_amdgcn_exp2f(s0[1]));
                pa.w[1] = pk2bf(__builtin_amdgcn_exp2f(s0[2]), __builtin_amdgcn_exp2f(s0[3]));
                pa.w[2] = pk2bf(__builtin_amdgcn_exp2f(s1[0]), __builtin_amdgcn_exp2f(s1[1]));
                pa.w[3] = pk2bf(__builtin_amdgcn_exp2f(s1[2]), __builtin_amdgcn_exp2f(s1[3]));
                oA0 = __builtin_amdgcn_mfma_f32_16x16x32_bf16(pa.v, vb0, oA0, 0, 0, 0);
                oA1 = __builtin_amdgcn_mfma_f32_16x16x32_bf16(pa.v, vb1, oA1, 0, 0, 0);
                lA  = __builtin_amdgcn_mfma_f32_16x16x32_bf16(pa.v, ones, lA, 0, 0, 0);
            }
            {
                f32x4 c0 = { bf2f(cB[0]), bf2f(cB[1]), bf2f(cB[2]), bf2f(cB[3]) };
                f32x4 c1 = { bf2f(cB[4]), bf2f(cB[5]), bf2f(cB[6]), bf2f(cB[7]) };
                const f32x4 s0 = __builtin_amdgcn_mfma_f32_16x16x32_bf16(ck0, qa1, c0, 0, 0, 0);
                const f32x4 s1 = __builtin_amdgcn_mfma_f32_16x16x32_bf16(ck1, qa1, c1, 0, 0, 0);
                union { bf16x8 v; u32 w[4]; } pa;
                pa.w[0] = pk2bf(__builtin_amdgcn_exp2f(s0[0]), __builtin_amdgcn_exp2f(s0[1]));
                pa.w[1] = pk2bf(__builtin_amdgcn_exp2f(s0[2]), __builtin_amdgcn_exp2f(s0[3]));
                pa.w[2] = pk2bf(__builtin_amdgcn_exp2f(s1[0]), __builtin_amdgcn_exp2f(s1[1]));
                pa.w[3] = pk2bf(__builtin_amdgcn_exp2f(s1[2]), __builtin_amdgcn_exp2f(s1[3]));
                oB0 = __builtin_amdgcn_mfma_f32_16x16x32_bf16(pa.v, vb0, oB0, 0, 0, 0);
                oB1 = __builtin_amdgcn_mfma_f32_16x16x32_bf16(pa.v, vb1, oB1, 0, 0, 0);
                lB  = __builtin_amdgcn_mfma_f32_16x16x32_bf16(pa.v, ones, lB, 0, 0, 0);
            }
        }
        #pragma unroll
        for (int half = 0; half < 2; ++half) {
            const f32x4 o0 = half ? oB0 : oA0;
            const f32x4 o1 = half ? oB1 : oA1;
            const f32x4 lc = half ? lB : lA;
            const int q0 = half ? q0b : q0a;
            #pragma unroll
            for (int r = 0; r < 4; ++r) {
                const float inv = 1.0f / lc[r];
                Os[wave][g * 4 + r][cl]      = f2bf(o0[r] * inv);
                Os[wave][g * 4 + r][16 + cl] = f2bf(o1[r] * inv);
            }
            const int row = lane >> 2, cg = (lane & 3) * 8;
            const int q = q0 + row;
            if (q < NTOK)
                *(float4*)(opb + (rowbase + q) * CDIM + h * HD + cg) =
                    *(const float4*)&Os[wave][row][cg];
        }
    }
}

// ---------------------------------------------------------------- proj GEMM
// Single-stage: opb tile staged once, W frags = coalesced frag-order loads,
// barrier-free K-loop, f32 out via 2-pass LDS-transpose epilogue.
__global__ __launch_bounds__(256, 3) void gemm_proj(
    const u16* __restrict__ opb, const u16* __restrict__ wpb,
    const float* __restrict__ bp, float* __restrict__ out)
{
    __shared__ __align__(16) u16 smem[128 * 200];
    u16*   Xs = smem;
    float* Cf = (float*)smem;                         // [64][104] f32
    const int f0 = blockIdx.x * 96, m0 = blockIdx.y * 128;
    const int tid = threadIdx.x;
    const int wave = tid >> 6, lane = tid & 63, g = lane >> 4, cl = lane & 15;
    const int wm = (wave >> 1) * 64, wf = (wave & 1) * 48;

    // stage once: 128 rows x 24 float4 units = 3072
    #pragma unroll
    for (int p = 0; p < 12; ++p) {
        const int u = tid + 256 * p;
        const int row = u / 24, c = u - row * 24;
        *(float4*)(Xs + row * 200 + c * 8) =
            *(const float4*)(opb + (size_t)(m0 + row) * CDIM + c * 8);
    }
    __syncthreads();

    f32x4 acc[4][3];
    #pragma unroll
    for (int t = 0; t < 4; ++t)
        #pragma unroll
        for (int s = 0; s < 3; ++s) acc[t][s] = (f32x4){0.f, 0.f, 0.f, 0.f};

    const u16* wbase = wpb + (size_t)(blockIdx.x * 6 + (wave & 1) * 3) * 3072 + lane * 8;
    #pragma unroll
    for (int kk = 0; kk < 6; ++kk) {
        const int kcol = kk * 32;
        bf16x8 a[4], bb[3];
        #pragma unroll
        for (int s = 0; s < 3; ++s)
            bb[s] = *(const bf16x8*)(wbase + s * 3072 + kk * 512);
        #pragma unroll
        for (int t = 0; t < 4; ++t)
            a[t] = *(const bf16x8*)(Xs + (wm + t * 16 + cl) * 200 + kcol + g * 8);
        #pragma unroll
        for (int t = 0; t < 4; ++t)
            #pragma unroll
            for (int s = 0; s < 3; ++s)
                acc[t][s] = __builtin_amdgcn_mfma_f32_16x16x32_bf16(a[t], bb[s], acc[t][s], 0, 0, 0);
    }

    #pragma unroll
    for (int half = 0; half < 2; ++half) {
        __syncthreads();
        if ((wave >> 1) == half) {
            #pragma unroll
            for (int s = 0; s < 3; ++s) {
                const float bv = bp[f0 + wf + s * 16 + cl];
                #pragma unroll
                for (int t = 0; t < 4; ++t)
                    #pragma unroll
                    for (int r = 0; r < 4; ++r)
                        Cf[(t * 16 + g * 4 + r) * 104 + wf + s * 16 + cl] = acc[t][s][r] + bv;
            }
        }
        __syncthreads();
        #pragma unroll
        for (int p = 0; p < 6; ++p) {
            const int u = tid + 256 * p;
            const int row = u / 24, c = u - row * 24;
            *(float4*)(out + (size_t)(m0 + half * 64 + row) * CDIM + f0 + c * 4) =
                *(const float4*)(Cf + row * 104 + c * 4);
        }
    }
}

// ---------------------------------------------------------------- launch
extern "C" void kernel_launch(void* const* d_in, const int* in_sizes, int n_in,
                              void* d_out, int out_size, void* d_ws, size_t ws_size,
                              hipStream_t stream) {
    const float* x     = (const float*)d_in[0];
    const float* wqkv  = (const float*)d_in[1];
    const float* bqkv  = (const float*)d_in[2];
    const float* wproj = (const float*)d_in[3];
    const float* bproj = (const float*)d_in[4];
    const float* btab  = (const float*)d_in[5];
    const int*   ridx  = (const int*)d_in[6];
    float* out = (float*)d_out;

    if (ws_size < WS_NEED) {
        hipLaunchKernelGGL(ws_too_small_sentinel, dim3(1), dim3(1), 0, stream, out);
        return;
    }
    char* ws = (char*)d_ws;
    u16*   qkvb = (u16*)(ws + OFF_QKVB);
    u16*   wqb  = (u16*)(ws + OFF_WQB);
    u16*   wpb  = (u16*)(ws + OFF_WPB);
    float* bqs  = (float*)(ws + OFF_BQS);
    u16*   bmb  = (u16*)(ws + OFF_BMB);
    u16*   opb  = (u16*)(ws + OFF_OPB);

    hipLaunchKernelGGL(cvt_small, dim3(3483), dim3(256), 0, stream,
                       wqkv, wproj, bqkv, btab, ridx, wqb, wpb, bqs, bmb);
    hipLaunchKernelGGL(gemm_qkv, dim3(6, NROWS / 128), dim3(256), 0, stream,
                       x, wqb, bqs, qkvb);
    hipLaunchKernelGGL(attn_mfma, dim3(BWIN, NH), dim3(256), 0, stream,
                       qkvb, bmb, opb);
    hipLaunchKernelGGL(gemm_proj, dim3(2, NROWS / 128), dim3(256), 0, stream,
                       opb, wpb, bproj, out);
}

// Round 8
// 255.940 us; speedup vs baseline: 1.6457x; 1.1108x over previous
//
#include <hip/hip_runtime.h>
#include <hip/hip_bf16.h>

#define BWIN 256
#define NTOK 343
#define CDIM 192
#define NH   6
#define HD   32
#define QKVF 576
#define NROWS (BWIN * NTOK)          // 87808
#define SCALE 0.17677669529663687f   // 1/sqrt(32)
#define LOG2E 1.4426950408889634f

typedef unsigned short u16;
typedef unsigned int   u32;
typedef short bf16x8 __attribute__((ext_vector_type(8)));
typedef float f32x4 __attribute__((ext_vector_type(4)));
typedef unsigned short u16x8 __attribute__((ext_vector_type(8)));

// ws layout (bytes). Interleaved qkvb [row][576] (R0 layout — the 6 head-
// blocks per window share cache lines on the same XCD; load-bearing for
// FETCH). wqb+bqs alias the opb head: dead after gemm_qkv, before attn
// writes opb. All three small tables are in MFMA-fragment order.
#define OFF_QKVB 0UL                 // u16 [87808][576] = 101,154,816
#define OFF_OPB  101154816UL         // u16 [87808][192] =  33,718,272
#define OFF_WQB  101154816UL         // u16 [36][6][64][8] = 221,184 (aliases opb)
#define OFF_BQS  101376000UL         // f32 [576] (aliases opb)
#define OFF_BMB  134873088UL         // u16 [6][22][11][64][8] = 1,486,848
#define OFF_WPB  136359936UL         // u16 [12][6][64][8] = 73,728
#define WS_NEED  136433664UL

__device__ __forceinline__ u16 f2bf(float f) {
    u32 u = __float_as_uint(f);
    u += 0x7FFFu + ((u >> 16) & 1u);           // RNE
    return (u16)(u >> 16);
}
__device__ __forceinline__ float bf2f(u16 h) {
    return __uint_as_float(((u32)h) << 16);
}
__device__ __forceinline__ u32 pk2bf(float a, float b) {
    union { __hip_bfloat162 h; u32 u; } v;
    v.h = __float22bfloat162_rn(make_float2(a, b));   // lo=a, hi=b
    return v.u;
}

__global__ void ws_too_small_sentinel(float* out) { out[0] = 1.0e6f; }

// ---------------------------------------------------------------- small converts
// Frag-order tables. W (both): [fb][kk][lane][8] where lane=(g<<4)|cl holds
// W[fb*16+cl][kk*32+g*8+e] — one coalesced bf16x8/lane B-fragment load.
// Bias: [h][qt(22)][jc(11)][lane][8], e<4 -> j=jc*32+g*4+e, e>=4 ->
// j=jc*32+16+g*4+(e-4); q=qt*16+cl clamped (pad outputs discarded);
// j>=343 = -10000 (validated in R5/R6).
__global__ __launch_bounds__(256) void cvt_small(
    const float* __restrict__ wq, const float* __restrict__ wp,
    const float* __restrict__ bq, const float* __restrict__ btab,
    const int* __restrict__ ridx,
    u16* __restrict__ wqb, u16* __restrict__ wpb,
    float* __restrict__ bqs, u16* __restrict__ bmb)
{
    const int i = blockIdx.x * 256 + threadIdx.x;
    if (i < 110592) {                                 // w_qkv -> frag order
        const int fb = i / 3072;                      // 6*512
        const int r1 = i - fb * 3072;
        const int kk = r1 >> 9;
        const int t  = r1 & 511;
        const int lane = t >> 3, e = t & 7;
        const int row = fb * 16 + (lane & 15);
        const int k   = kk * 32 + (lane >> 4) * 8 + e;
        wqb[i] = f2bf(wq[row * 192 + k] * (row < CDIM ? SCALE * LOG2E : 1.0f));
    } else if (i < 147456) {                          // w_proj -> frag order
        const int u = i - 110592;
        const int fb = u / 3072;
        const int r1 = u - fb * 3072;
        const int kk = r1 >> 9;
        const int t  = r1 & 511;
        const int lane = t >> 3, e = t & 7;
        const int row = fb * 16 + (lane & 15);
        const int k   = kk * 32 + (lane >> 4) * 8 + e;
        wpb[u] = f2bf(wp[row * 192 + k]);
    } else if (i < 148032) {
        const int f = i - 147456;
        bqs[f] = bq[f] * (f < CDIM ? SCALE * LOG2E : 1.0f);
    } else if (i < 891456) {                          // frag-order bias
        const int u = i - 148032;                     // [0, 743424)
        const int hh = u / 123904;                    // 22*11*512
        const int rem = u - hh * 123904;
        const int qt = rem / 5632;                    // 11*512
        const int rem2 = rem - qt * 5632;
        const int jc = rem2 >> 9;
        const int t = rem2 & 511;
        const int lane = t >> 3, e = t & 7;
        const int cl = lane & 15, g = lane >> 4;
        const int q = min(qt * 16 + cl, NTOK - 1);
        const int j = jc * 32 + ((e < 4) ? (g * 4 + e) : (16 + g * 4 + (e - 4)));
        const float v = (j < NTOK) ? btab[ridx[q * NTOK + j] * NH + hh] * LOG2E
                                   : -10000.0f;
        bmb[u] = f2bf(v);
    }
}

// ---------------------------------------------------------------- qkv GEMM
// Single X read: 64-row tile staged ONCE into LDS (f32->bf16 fused), then
// loop over all 6 f-chunks in-block (was grid-parallel -> 6x X re-read,
// measured FETCH 200MB vs 67MB ideal in R7). W frags coalesced frag-order.
// Waves 2M(32rows)x2F(48cols), acc[2][3]. LDS 38.9KB -> 4 blocks/CU.
__global__ __launch_bounds__(256, 4) void gemm_qkv(
    const float* __restrict__ x, const u16* __restrict__ wqb,
    const float* __restrict__ bqs, u16* __restrict__ qkvb)
{
    __shared__ __align__(16) u16 Xs[64 * 200];        // X tile, live whole kernel
    __shared__ __align__(16) u16 Ct[64 * 104];        // epilogue transpose buffer
    const int m0 = blockIdx.x * 64;
    const int tid = threadIdx.x;
    const int wave = tid >> 6, lane = tid & 63, g = lane >> 4, cl = lane & 15;
    const int wm = (wave >> 1) * 32, wf = (wave & 1) * 48;

    // stage X once: 64 rows x 48 float4 units = 3072 (12 passes of 256)
    #pragma unroll
    for (int p = 0; p < 12; ++p) {
        const int u = tid + 256 * p;
        const int row = u / 48, c = u - row * 48;
        const float4 v = *(const float4*)(x + (size_t)(m0 + row) * CDIM + c * 4);
        *(uint2*)(Xs + row * 200 + c * 4) = make_uint2(pk2bf(v.x, v.y), pk2bf(v.z, v.w));
    }
    __syncthreads();

    for (int fc = 0; fc < 6; ++fc) {
        const int f0 = fc * 96;
        f32x4 acc[2][3];
        #pragma unroll
        for (int t = 0; t < 2; ++t)
            #pragma unroll
            for (int s = 0; s < 3; ++s) acc[t][s] = (f32x4){0.f, 0.f, 0.f, 0.f};

        const u16* wbase = wqb + (size_t)(fc * 6 + (wave & 1) * 3) * 3072 + lane * 8;
        #pragma unroll
        for (int kk = 0; kk < 6; ++kk) {
            const int kcol = kk * 32;
            bf16x8 a[2], bb[3];
            #pragma unroll
            for (int s = 0; s < 3; ++s)
                bb[s] = *(const bf16x8*)(wbase + s * 3072 + kk * 512);
            #pragma unroll
            for (int t = 0; t < 2; ++t)
                a[t] = *(const bf16x8*)(Xs + (wm + t * 16 + cl) * 200 + kcol + g * 8);
            #pragma unroll
            for (int t = 0; t < 2; ++t)
                #pragma unroll
                for (int s = 0; s < 3; ++s)
                    acc[t][s] = __builtin_amdgcn_mfma_f32_16x16x32_bf16(a[t], bb[s], acc[t][s], 0, 0, 0);
        }

        __syncthreads();                              // prev fc's Ct reads done
        #pragma unroll
        for (int s = 0; s < 3; ++s) {
            const float bv = bqs[f0 + wf + s * 16 + cl];
            #pragma unroll
            for (int t = 0; t < 2; ++t) {
                const int row = wm + t * 16 + g * 4;
                const int col = wf + s * 16 + cl;
                const u32 p01 = pk2bf(acc[t][s][0] + bv, acc[t][s][1] + bv);
                const u32 p23 = pk2bf(acc[t][s][2] + bv, acc[t][s][3] + bv);
                Ct[(row + 0) * 104 + col] = (u16)p01;
                Ct[(row + 1) * 104 + col] = (u16)(p01 >> 16);
                Ct[(row + 2) * 104 + col] = (u16)p23;
                Ct[(row + 3) * 104 + col] = (u16)(p23 >> 16);
            }
        }
        __syncthreads();
        #pragma unroll
        for (int p = 0; p < 3; ++p) {                 // coalesced 16B stores
            const int u = tid + 256 * p;
            const int row = u / 12, c = u - row * 12;
            *(float4*)(qkvb + (size_t)(m0 + row) * QKVF + f0 + c * 8) =
                *(const float4*)(Ct + row * 104 + c * 8);
        }
    }
}

// ---------------------------------------------------------------- attention
// R7-verbatim: interleaved layout, clamps, occ 4, frag-order coalesced bias.
__global__ __launch_bounds__(256, 4) void attn_mfma(
    const u16* __restrict__ qkvb, const u16* __restrict__ bmb,
    u16* __restrict__ opb)
{
    __shared__ u16 Vt[HD][360];      // [d][j-slot] 23040 B
    __shared__ u16 Os[4][16][32];    // per-wave O staging 4096 B
    const int b = blockIdx.x, h = blockIdx.y;
    const int tid = threadIdx.x;
    const int wave = tid >> 6, lane = tid & 63, g = lane >> 4, cl = lane & 15;
    const size_t rowbase = (size_t)b * NTOK;

    for (int u = tid; u < 1408; u += 256) {           // V stage, sigma slots
        const int row = u >> 2, seg = u & 3;
        union { float4 f; u16 hx[8]; } vv;
        vv.f = make_float4(0.f, 0.f, 0.f, 0.f);
        if (row < NTOK)
            vv.f = *(const float4*)(qkvb + (rowbase + row) * QKVF + 2 * CDIM + h * HD + seg * 8);
        const int jl = row & 31;
        const int slot = (jl < 16) ? ((jl >> 2) << 3) + (jl & 3)
                                   : (((jl - 16) >> 2) << 3) + 4 + (jl & 3);
        const int pcol = (row & ~31) + slot;
        #pragma unroll
        for (int e = 0; e < 8; ++e) Vt[seg * 8 + e][pcol] = vv.hx[e];
    }
    __syncthreads();

    bf16x8 ones;
    #pragma unroll
    for (int e = 0; e < 8; ++e) ones[e] = (short)0x3F80;

    for (int base = wave * 2; base < 22; base += 8) { // 11 pairs total
        const int q0a = base * 16, q0b = q0a + 16;
        const bf16x8 qa0 = *(const bf16x8*)(qkvb + (rowbase + min(q0a + cl, NTOK - 1)) * QKVF + h * HD + g * 8);
        const bf16x8 qa1 = *(const bf16x8*)(qkvb + (rowbase + min(q0b + cl, NTOK - 1)) * QKVF + h * HD + g * 8);
        const u16* bpA = bmb + ((size_t)(h * 22 + base) * 11) * 512 + lane * 8;
        const u16* bpB = bpA + 5632;                  // next q-tile (11*512)

        bf16x8 kb0 = *(const bf16x8*)(qkvb + (rowbase + cl) * QKVF + CDIM + h * HD + g * 8);
        bf16x8 kb1 = *(const bf16x8*)(qkvb + (rowbase + 16 + cl) * QKVF + CDIM + h * HD + g * 8);
        u16x8 bA = *(const u16x8*)(bpA);
        u16x8 bB = *(const u16x8*)(bpB);

        f32x4 oA0 = {0,0,0,0}, oA1 = {0,0,0,0}, lA = {0,0,0,0};
        f32x4 oB0 = {0,0,0,0}, oB1 = {0,0,0,0}, lB = {0,0,0,0};

        for (int jc = 0; jc < 11; ++jc) {
            const int j0 = jc * 32;
            const bf16x8 ck0 = kb0, ck1 = kb1;
            const u16x8 cA = bA, cB = bB;
            if (jc < 10) {
                const int jn = j0 + 32;
                kb0 = *(const bf16x8*)(qkvb + (rowbase + min(jn + cl, NTOK - 1)) * QKVF + CDIM + h * HD + g * 8);
                kb1 = *(const bf16x8*)(qkvb + (rowbase + min(jn + 16 + cl, NTOK - 1)) * QKVF + CDIM + h * HD + g * 8);
                bA = *(const u16x8*)(bpA + (jc + 1) * 512);
                bB = *(const u16x8*)(bpB + (jc + 1) * 512);
            }
            const bf16x8 vb0 = *(const bf16x8*)&Vt[cl][j0 + g * 8];
            const bf16x8 vb1 = *(const bf16x8*)&Vt[16 + cl][j0 + g * 8];

            {
                f32x4 c0 = { bf2f(cA[0]), bf2f(cA[1]), bf2f(cA[2]), bf2f(cA[3]) };
                f32x4 c1 = { bf2f(cA[4]), bf2f(cA[5]), bf2f(cA[6]), bf2f(cA[7]) };
                const f32x4 s0 = __builtin_amdgcn_mfma_f32_16x16x32_bf16(ck0, qa0, c0, 0, 0, 0);
                const f32x4 s1 = __builtin_amdgcn_mfma_f32_16x16x32_bf16(ck1, qa0, c1, 0, 0, 0);
                union { bf16x8 v; u32 w[4]; } pa;
                pa.w[0] = pk2bf(__builtin_amdgcn_exp2f(s0[0]), __builtin_amdgcn_exp2f(s0[1]));
                pa.w[1] = pk2bf(__builtin_amdgcn_exp2f(s0[2]), __builtin_amdgcn_exp2f(s0[3]));
                pa.w[2] = pk2bf(__builtin_amdgcn_exp2f(s1[0]), __builtin_amdgcn_exp2f(s1[1]));
                pa.w[3] = pk2bf(__builtin_amdgcn_exp2f(s1[2]), __builtin_amdgcn_exp2f(s1[3]));
                oA0 = __builtin_amdgcn_mfma_f32_16x16x32_bf16(pa.v, vb0, oA0, 0, 0, 0);
                oA1 = __builtin_amdgcn_mfma_f32_16x16x32_bf16(pa.v, vb1, oA1, 0, 0, 0);
                lA  = __builtin_amdgcn_mfma_f32_16x16x32_bf16(pa.v, ones, lA, 0, 0, 0);
            }
            {
                f32x4 c0 = { bf2f(cB[0]), bf2f(cB[1]), bf2f(cB[2]), bf2f(cB[3]) };
                f32x4 c1 = { bf2f(cB[4]), bf2f(cB[5]), bf2f(cB[6]), bf2f(cB[7]) };
                const f32x4 s0 = __builtin_amdgcn_mfma_f32_16x16x32_bf16(ck0, qa1, c0, 0, 0, 0);
                const f32x4 s1 = __builtin_amdgcn_mfma_f32_16x16x32_bf16(ck1, qa1, c1, 0, 0, 0);
                union { bf16x8 v; u32 w[4]; } pa;
                pa.w[0] = pk2bf(__builtin_amdgcn_exp2f(s0[0]), __builtin_amdgcn_exp2f(s0[1]));
                pa.w[1] = pk2bf(__builtin_amdgcn_exp2f(s0[2]), __builtin_amdgcn_exp2f(s0[3]));
                pa.w[2] = pk2bf(__builtin_amdgcn_exp2f(s1[0]), __builtin_amdgcn_exp2f(s1[1]));
                pa.w[3] = pk2bf(__builtin_amdgcn_exp2f(s1[2]), __builtin_amdgcn_exp2f(s1[3]));
                oB0 = __builtin_amdgcn_mfma_f32_16x16x32_bf16(pa.v, vb0, oB0, 0, 0, 0);
                oB1 = __builtin_amdgcn_mfma_f32_16x16x32_bf16(pa.v, vb1, oB1, 0, 0, 0);
                lB  = __builtin_amdgcn_mfma_f32_16x16x32_bf16(pa.v, ones, lB, 0, 0, 0);
            }
        }
        #pragma unroll
        for (int half = 0; half < 2; ++half) {
            const f32x4 o0 = half ? oB0 : oA0;
            const f32x4 o1 = half ? oB1 : oA1;
            const f32x4 lc = half ? lB : lA;
            const int q0 = half ? q0b : q0a;
            #pragma unroll
            for (int r = 0; r < 4; ++r) {
                const float inv = 1.0f / lc[r];
                Os[wave][g * 4 + r][cl]      = f2bf(o0[r] * inv);
                Os[wave][g * 4 + r][16 + cl] = f2bf(o1[r] * inv);
            }
            const int row = lane >> 2, cg = (lane & 3) * 8;
            const int q = q0 + row;
            if (q < NTOK)
                *(float4*)(opb + (rowbase + q) * CDIM + h * HD + cg) =
                    *(const float4*)&Os[wave][row][cg];
        }
    }
}

// ---------------------------------------------------------------- proj GEMM
// R7-verbatim: opb tile staged once, W frags coalesced frag-order,
// barrier-free K-loop, f32 out via 2-pass LDS-transpose epilogue.
__global__ __launch_bounds__(256, 3) void gemm_proj(
    const u16* __restrict__ opb, const u16* __restrict__ wpb,
    const float* __restrict__ bp, float* __restrict__ out)
{
    __shared__ __align__(16) u16 smem[128 * 200];
    u16*   Xs = smem;
    float* Cf = (float*)smem;                         // [64][104] f32
    const int f0 = blockIdx.x * 96, m0 = blockIdx.y * 128;
    const int tid = threadIdx.x;
    const int wave = tid >> 6, lane = tid & 63, g = lane >> 4, cl = lane & 15;
    const int wm = (wave >> 1) * 64, wf = (wave & 1) * 48;

    // stage once: 128 rows x 24 float4 units = 3072
    #pragma unroll
    for (int p = 0; p < 12; ++p) {
        const int u = tid + 256 * p;
        const int row = u / 24, c = u - row * 24;
        *(float4*)(Xs + row * 200 + c * 8) =
            *(const float4*)(opb + (size_t)(m0 + row) * CDIM + c * 8);
    }
    __syncthreads();

    f32x4 acc[4][3];
    #pragma unroll
    for (int t = 0; t < 4; ++t)
        #pragma unroll
        for (int s = 0; s < 3; ++s) acc[t][s] = (f32x4){0.f, 0.f, 0.f, 0.f};

    const u16* wbase = wpb + (size_t)(blockIdx.x * 6 + (wave & 1) * 3) * 3072 + lane * 8;
    #pragma unroll
    for (int kk = 0; kk < 6; ++kk) {
        const int kcol = kk * 32;
        bf16x8 a[4], bb[3];
        #pragma unroll
        for (int s = 0; s < 3; ++s)
            bb[s] = *(const bf16x8*)(wbase + s * 3072 + kk * 512);
        #pragma unroll
        for (int t = 0; t < 4; ++t)
            a[t] = *(const bf16x8*)(Xs + (wm + t * 16 + cl) * 200 + kcol + g * 8);
        #pragma unroll
        for (int t = 0; t < 4; ++t)
            #pragma unroll
            for (int s = 0; s < 3; ++s)
                acc[t][s] = __builtin_amdgcn_mfma_f32_16x16x32_bf16(a[t], bb[s], acc[t][s], 0, 0, 0);
    }

    #pragma unroll
    for (int half = 0; half < 2; ++half) {
        __syncthreads();
        if ((wave >> 1) == half) {
            #pragma unroll
            for (int s = 0; s < 3; ++s) {
                const float bv = bp[f0 + wf + s * 16 + cl];
                #pragma unroll
                for (int t = 0; t < 4; ++t)
                    #pragma unroll
                    for (int r = 0; r < 4; ++r)
                        Cf[(t * 16 + g * 4 + r) * 104 + wf + s * 16 + cl] = acc[t][s][r] + bv;
            }
        }
        __syncthreads();
        #pragma unroll
        for (int p = 0; p < 6; ++p) {
            const int u = tid + 256 * p;
            const int row = u / 24, c = u - row * 24;
            *(float4*)(out + (size_t)(m0 + half * 64 + row) * CDIM + f0 + c * 4) =
                *(const float4*)(Cf + row * 104 + c * 4);
        }
    }
}

// ---------------------------------------------------------------- launch
extern "C" void kernel_launch(void* const* d_in, const int* in_sizes, int n_in,
                              void* d_out, int out_size, void* d_ws, size_t ws_size,
                              hipStream_t stream) {
    const float* x     = (const float*)d_in[0];
    const float* wqkv  = (const float*)d_in[1];
    const float* bqkv  = (const float*)d_in[2];
    const float* wproj = (const float*)d_in[3];
    const float* bproj = (const float*)d_in[4];
    const float* btab  = (const float*)d_in[5];
    const int*   ridx  = (const int*)d_in[6];
    float* out = (float*)d_out;

    if (ws_size < WS_NEED) {
        hipLaunchKernelGGL(ws_too_small_sentinel, dim3(1), dim3(1), 0, stream, out);
        return;
    }
    char* ws = (char*)d_ws;
    u16*   qkvb = (u16*)(ws + OFF_QKVB);
    u16*   wqb  = (u16*)(ws + OFF_WQB);
    u16*   wpb  = (u16*)(ws + OFF_WPB);
    float* bqs  = (float*)(ws + OFF_BQS);
    u16*   bmb  = (u16*)(ws + OFF_BMB);
    u16*   opb  = (u16*)(ws + OFF_OPB);

    hipLaunchKernelGGL(cvt_small, dim3(3483), dim3(256), 0, stream,
                       wqkv, wproj, bqkv, btab, ridx, wqb, wpb, bqs, bmb);
    hipLaunchKernelGGL(gemm_qkv, dim3(NROWS / 64), dim3(256), 0, stream,
                       x, wqb, bqs, qkvb);
    hipLaunchKernelGGL(attn_mfma, dim3(BWIN, NH), dim3(256), 0, stream,
                       qkvb, bmb, opb);
    hipLaunchKernelGGL(gemm_proj, dim3(2, NROWS / 128), dim3(256), 0, stream,
                       opb, wpb, bproj, out);
}